// Round 1
// baseline (6275.507 us; speedup 1.0000x reference)
//
#include <hip/hip_runtime.h>
#include <hip/hip_bf16.h>
#include <cmath>

// Problem constants (from reference)
#define L_SEQ  1024
#define BATCH  16
#define NOUT   512          // n
#define DIN    1024         // 2n = layer input dim
#define NBIG   3072         // 6n = GEMM N
#define NLAYERS 4

// ---------------- embedding gather ----------------
// grid: L*B blocks, 256 threads; each block copies one 1024-float row as float4.
__global__ void embed_kernel(const int* __restrict__ tok,
                             const float* __restrict__ emb,
                             float* __restrict__ x) {
    int t = blockIdx.x;                 // token index 0..L*B-1
    int row = tok[t];
    const float4* src = (const float4*)(emb + (size_t)row * DIN);
    float4* dst = (float4*)(x + (size_t)t * DIN);
    dst[threadIdx.x] = src[threadIdx.x];
}

// ---------------- fp32 tiled GEMM ----------------
// C[M,N] = A[M,K] * B[K,N], all row-major. BM=BN=128, BK=16, 256 threads,
// 8x8 microtile per thread. Cols per thread: {tn4..tn4+3} and {64+tn4..+3}
// (keeps LDS b-reads at <=2-way bank aliasing, which is free).
#define BM 128
#define BN 128
#define BK 16

__global__ __launch_bounds__(256)
void gemm_f32(const float* __restrict__ A, const float* __restrict__ Bm,
              float* __restrict__ C, int M, int N, int K) {
    __shared__ float As[BK][BM];   // k-major so a-reads are b128 broadcast
    __shared__ float Bs[BK][BN];
    const int tid = threadIdx.x;
    const int bm = blockIdx.y, bn = blockIdx.x;
    const int tm  = (tid >> 4) * 8;       // row base 0..120
    const int tn4 = (tid & 15) * 4;       // col base

    float acc[8][8] = {};                 // [row][colgroup: 0..3 -> tn4+j, 4..7 -> 64+tn4+j]

    const float* Ab = A + (size_t)bm * BM * K;
    const float* Bb = Bm + (size_t)bn * BN;

    for (int k0 = 0; k0 < K; k0 += BK) {
        // A tile: 128 rows x 16 cols = 512 float4. thread -> (r = tid/4 + 64*i, c = (tid&3)*4)
        #pragma unroll
        for (int i = 0; i < 2; i++) {
            int r = i * 64 + (tid >> 2);
            int c = (tid & 3) * 4;
            float4 v = *(const float4*)(Ab + (size_t)r * K + k0 + c);
            As[c + 0][r] = v.x;
            As[c + 1][r] = v.y;
            As[c + 2][r] = v.z;
            As[c + 3][r] = v.w;
        }
        // B tile: 16 rows x 128 cols = 512 float4. thread -> (r = tid/32 + 8*i, c = (tid&31)*4)
        #pragma unroll
        for (int i = 0; i < 2; i++) {
            int r = i * 8 + (tid >> 5);
            int c = (tid & 31) * 4;
            *(float4*)(&Bs[r][c]) = *(const float4*)(Bb + (size_t)(k0 + r) * N + c);
        }
        __syncthreads();

        #pragma unroll
        for (int k = 0; k < BK; k++) {
            float4 a0 = *(const float4*)(&As[k][tm]);
            float4 a1 = *(const float4*)(&As[k][tm + 4]);
            float4 b0 = *(const float4*)(&Bs[k][tn4]);
            float4 b1 = *(const float4*)(&Bs[k][64 + tn4]);
            float a[8] = {a0.x, a0.y, a0.z, a0.w, a1.x, a1.y, a1.z, a1.w};
            float b[8] = {b0.x, b0.y, b0.z, b0.w, b1.x, b1.y, b1.z, b1.w};
            #pragma unroll
            for (int i2 = 0; i2 < 8; i2++)
                #pragma unroll
                for (int j = 0; j < 8; j++)
                    acc[i2][j] += a[i2] * b[j];
        }
        __syncthreads();
    }

    float* Cb = C + (size_t)(bm * BM) * N + bn * BN;
    #pragma unroll
    for (int i2 = 0; i2 < 8; i2++) {
        float4 v0 = make_float4(acc[i2][0], acc[i2][1], acc[i2][2], acc[i2][3]);
        float4 v1 = make_float4(acc[i2][4], acc[i2][5], acc[i2][6], acc[i2][7]);
        *(float4*)(Cb + (size_t)(tm + i2) * N + tn4) = v0;
        *(float4*)(Cb + (size_t)(tm + i2) * N + 64 + tn4) = v1;
    }
}

// ---------------- SRU scan (both directions), in-place on x ----------------
// u: (L, B, 6n); dir d uses slice [d*3n, (d+1)*3n) = [xt | f_raw | r_raw].
// x: (L, B, 2n); dir d reads xp and writes h at [..., d*n + i] (in place, safe:
// each element read-then-written once by its own thread, GEMM already consumed x).
// grid: B * 2 * (n/64) = 256 blocks of 64 threads -> 1 wave per CU.
__global__ __launch_bounds__(64)
void sru_scan(const float* __restrict__ u, float* __restrict__ x,
              const float* __restrict__ bias, float* __restrict__ c_out) {
    const int chunks = NOUT / 64;       // 8
    int blk = blockIdx.x;
    int chunk = blk & (chunks - 1);
    int d = (blk >> 3) & 1;
    int b = blk >> 4;
    int i = chunk * 64 + threadIdx.x;   // feature 0..n-1

    float bf = bias[d * NOUT + i];
    float br = bias[2 * NOUT + d * NOUT + i];

    const float* ub = u + (size_t)b * NBIG + (size_t)d * 3 * NOUT;
    float* xb = x + (size_t)b * DIN + (size_t)d * NOUT + i;
    const size_t su = (size_t)BATCH * NBIG;
    const size_t sx = (size_t)BATCH * DIN;

    float c = 0.f;
    if (d == 0) {
        #pragma unroll 8
        for (int t = 0; t < L_SEQ; t++) {
            const float* ut = ub + (size_t)t * su;
            float xt = ut[i];
            float fr = ut[NOUT + i];
            float rr = ut[2 * NOUT + i];
            float xp = xb[(size_t)t * sx];
            float f = 1.f / (1.f + __expf(-(fr + bf)));
            float r = 1.f / (1.f + __expf(-(rr + br)));
            c = f * c + (1.f - f) * xt;
            float h = r * tanhf(c) + (1.f - r) * xp;
            xb[(size_t)t * sx] = h;
        }
    } else {
        #pragma unroll 8
        for (int t = L_SEQ - 1; t >= 0; t--) {
            const float* ut = ub + (size_t)t * su;
            float xt = ut[i];
            float fr = ut[NOUT + i];
            float rr = ut[2 * NOUT + i];
            float xp = xb[(size_t)t * sx];
            float f = 1.f / (1.f + __expf(-(fr + bf)));
            float r = 1.f / (1.f + __expf(-(rr + br)));
            c = f * c + (1.f - f) * xt;
            float h = r * tanhf(c) + (1.f - r) * xp;
            xb[(size_t)t * sx] = h;
        }
    }
    c_out[(size_t)b * DIN + (size_t)d * NOUT + i] = c;
}

// ---------------- launch ----------------
// Inputs (setup_inputs order): rnn_input(int32 L*B), input_lengths(int32 B, UNUSED),
// emb(f32 32000x1024), Ws(f32 4x1024x3072), bs(f32 4x2048).
// d_out: [ x_final (L*B*1024) | hidden (4*B*1024) ] f32.
// Workspace: u buffer (L*B*3072 f32 = 192 MB).
extern "C" void kernel_launch(void* const* d_in, const int* in_sizes, int n_in,
                              void* d_out, int out_size, void* d_ws, size_t ws_size,
                              hipStream_t stream) {
    const int*   tok = (const int*)d_in[0];
    // d_in[1] = input_lengths: unused by reference
    const float* emb = (const float*)d_in[2];
    const float* Ws  = (const float*)d_in[3];
    const float* bs  = (const float*)d_in[4];

    float* out    = (float*)d_out;
    float* x      = out;                                        // (L,B,2n)
    float* hidden = out + (size_t)L_SEQ * BATCH * DIN;          // (4,B,2n)
    float* u      = (float*)d_ws;                               // (L,B,6n)

    embed_kernel<<<L_SEQ * BATCH, 256, 0, stream>>>(tok, emb, x);

    for (int l = 0; l < NLAYERS; l++) {
        const float* W = Ws + (size_t)l * DIN * NBIG;
        const float* b = bs + (size_t)l * 4 * NOUT;
        dim3 grid(NBIG / BN, (L_SEQ * BATCH) / BM);
        gemm_f32<<<grid, 256, 0, stream>>>(x, W, u, L_SEQ * BATCH, NBIG, DIN);
        sru_scan<<<BATCH * 2 * (NOUT / 64), 64, 0, stream>>>(
            u, x, b, hidden + (size_t)l * BATCH * DIN);
    }
}

// Round 2
// 2976.055 us; speedup vs baseline: 2.1087x; 2.1087x over previous
//
#include <hip/hip_runtime.h>
#include <hip/hip_bf16.h>
#include <cmath>

// Problem constants
#define L_SEQ  1024
#define BATCH  16
#define NOUT   512          // n
#define DIN    1024         // 2n = layer input dim = GEMM K
#define NBIG   3072         // 6n = GEMM N
#define NLAYERS 4
#define NTOK   (L_SEQ * BATCH)   // 16384 = GEMM M

typedef __attribute__((ext_vector_type(8))) short bf16x8;
typedef __attribute__((ext_vector_type(4))) float f32x4;

__device__ __forceinline__ unsigned short f2bf(float f) {
    unsigned x = __float_as_uint(f);
    unsigned r = (x + 0x7fffu + ((x >> 16) & 1u)) >> 16;   // round-to-nearest-even
    return (unsigned short)r;
}
__device__ __forceinline__ float bf2f(unsigned hv) {
    return __uint_as_float(hv << 16);
}
__device__ __forceinline__ void async16(const void* g, const void* l) {
    __builtin_amdgcn_global_load_lds(
        (const __attribute__((address_space(1))) unsigned int*)g,
        (__attribute__((address_space(3))) unsigned int*)l, 16, 0, 0);
}

// ---------------- W convert + transpose: W(1024,3072) f32 -> Wt(3072,1024) bf16 ----------------
__global__ __launch_bounds__(256)
void transpose_w(const float* __restrict__ Ws, unsigned short* __restrict__ Wt) {
    __shared__ float tile[32][33];
    int l = blockIdx.z;
    const float* W = Ws + (size_t)l * DIN * NBIG;
    unsigned short* Wo = Wt + (size_t)l * NBIG * DIN;
    int n0 = blockIdx.x * 32, k0 = blockIdx.y * 32;
    int tx = threadIdx.x & 31, ty = threadIdx.x >> 5;   // ty 0..7
    #pragma unroll
    for (int i = 0; i < 4; i++)
        tile[ty + 8 * i][tx] = W[(size_t)(k0 + ty + 8 * i) * NBIG + n0 + tx];
    __syncthreads();
    #pragma unroll
    for (int i = 0; i < 4; i++)
        Wo[(size_t)(n0 + ty + 8 * i) * DIN + k0 + tx] = f2bf(tile[tx][ty + 8 * i]);
}

// ---------------- embedding gather: write x fp32 + xbf bf16 ----------------
__global__ void embed_kernel(const int* __restrict__ tok,
                             const float* __restrict__ emb,
                             float* __restrict__ x,
                             unsigned short* __restrict__ xbf) {
    int t = blockIdx.x;
    int row = tok[t];
    float4 v = ((const float4*)(emb + (size_t)row * DIN))[threadIdx.x];
    ((float4*)(x + (size_t)t * DIN))[threadIdx.x] = v;
    ushort4 h;
    h.x = f2bf(v.x); h.y = f2bf(v.y); h.z = f2bf(v.z); h.w = f2bf(v.w);
    ((ushort4*)(xbf + (size_t)t * DIN))[threadIdx.x] = h;
}

// ---------------- bf16 MFMA GEMM: u = x @ W ----------------
// A = xbf (M,1024) bf16 row-major; B = Wt (3072,1024) bf16 row-major (i.e. W^T).
// 128x128 block tile, BK=32, 4 waves in 2x2, each wave 64x64 via 4x4 of 16x16x32 MFMA.
// LDS tiles staged via global_load_lds width 16 with SOURCE-side XOR swizzle:
// logical chunk (row r, kchunk c) stored at slot r*4 + (c ^ ((r>>1)&3)) so that
// frag ds_read_b128 (lanes 0-15 reading 16 rows, same kchunk) is <=2-way per bank. Free.
// Output split: plane 0 (xt) -> u_xt fp32 (M,1024); planes 1,2 (f,r) -> u_fr bf16
// interleaved pairs (M, 1024 pairs): [tok][dir*512 + feat] = (f_raw, r_raw).
__global__ __launch_bounds__(256)
void gemm_bf16(const unsigned short* __restrict__ Abf,
               const unsigned short* __restrict__ Bt,
               float* __restrict__ u_xt,
               unsigned short* __restrict__ u_fr) {
    __shared__ __align__(16) unsigned short As[128 * 32];
    __shared__ __align__(16) unsigned short Bs[128 * 32];

    const int tid  = threadIdx.x;
    const int lane = tid & 63;
    const int w    = tid >> 6;
    const int wm   = w & 1, wn = w >> 1;
    const int quad = lane >> 4, l16 = lane & 15;

    const int M0 = blockIdx.y * 128;
    const int N0 = blockIdx.x * 128;

    f32x4 acc[4][4];
    #pragma unroll
    for (int i = 0; i < 4; i++)
        #pragma unroll
        for (int j = 0; j < 4; j++)
            acc[i][j] = (f32x4){0.f, 0.f, 0.f, 0.f};

    // staging source coordinates for this lane (within a 16-row group)
    const int sr = lane >> 2;                         // row 0..15
    const int sc = (lane & 3) ^ ((lane >> 3) & 3);    // swizzled k-chunk 0..3

    for (int k0 = 0; k0 < DIN; k0 += 32) {
        #pragma unroll
        for (int s = 0; s < 2; s++) {
            int rbase = w * 32 + s * 16;              // wave-uniform row group
            int r = rbase + sr;
            async16(Abf + (size_t)(M0 + r) * DIN + k0 + sc * 8, &As[rbase * 32]);
            async16(Bt  + (size_t)(N0 + r) * DIN + k0 + sc * 8, &Bs[rbase * 32]);
        }
        __syncthreads();   // drains vmcnt before barrier (compiler-inserted)

        bf16x8 af[4], bg[4];
        #pragma unroll
        for (int t = 0; t < 4; t++) {
            int ra = wm * 64 + t * 16 + l16;
            int ca = quad ^ ((ra >> 1) & 3);
            af[t] = *(const bf16x8*)&As[ra * 32 + ca * 8];
            int rb = wn * 64 + t * 16 + l16;
            int cb = quad ^ ((rb >> 1) & 3);
            bg[t] = *(const bf16x8*)&Bs[rb * 32 + cb * 8];
        }
        #pragma unroll
        for (int i = 0; i < 4; i++)
            #pragma unroll
            for (int j = 0; j < 4; j++)
                acc[i][j] = __builtin_amdgcn_mfma_f32_16x16x32_bf16(af[i], bg[j], acc[i][j], 0, 0, 0);
        __syncthreads();
    }

    // epilogue: D[row=quad*4+reg][col=l16] per 16x16 tile
    #pragma unroll
    for (int i = 0; i < 4; i++) {
        int gm = M0 + wm * 64 + i * 16 + quad * 4;
        #pragma unroll
        for (int j = 0; j < 4; j++) {
            int gn = N0 + wn * 64 + j * 16 + l16;
            int dir  = gn >= 3 * NOUT;
            int jj   = gn - dir * 3 * NOUT;
            int plane = jj >> 9;          // 0:xt 1:f 2:r (uniform per tile)
            int feat  = jj & 511;
            if (plane == 0) {
                float* p = u_xt + (size_t)gm * DIN + dir * NOUT + feat;
                #pragma unroll
                for (int r = 0; r < 4; r++) p[(size_t)r * DIN] = acc[i][j][r];
            } else {
                unsigned short* p = u_fr + (size_t)gm * 2048 + (size_t)(dir * NOUT + feat) * 2 + (plane - 1);
                #pragma unroll
                for (int r = 0; r < 4; r++) p[(size_t)r * 2048] = f2bf(acc[i][j][r]);
            }
        }
    }
}

// ---------------- SRU scan, in-place on x, fused bf16 cast for next layer ----------------
__global__ __launch_bounds__(64)
void sru_scan(const float* __restrict__ u_xt, const unsigned* __restrict__ u_fr32,
              float* __restrict__ x, unsigned short* __restrict__ xbf,
              const float* __restrict__ bias, float* __restrict__ c_out, int write_bf) {
    int blk = blockIdx.x;
    int chunk = blk & 7;
    int d = (blk >> 3) & 1;
    int b = blk >> 4;
    int i = chunk * 64 + threadIdx.x;

    float bf = bias[d * NOUT + i];
    float br = bias[2 * NOUT + d * NOUT + i];

    const size_t base = (size_t)b * DIN + d * NOUT + i;   // same index for u_xt/u_fr32/x/xbf
    const size_t stride = (size_t)BATCH * DIN;            // 16384 per time step

    float c = 0.f;
    if (d == 0) {
        #pragma unroll 8
        for (int t = 0; t < L_SEQ; t++) {
            size_t idx = base + (size_t)t * stride;
            float xt = u_xt[idx];
            unsigned fr = u_fr32[idx];
            float xp = x[idx];
            float f = 1.f / (1.f + __expf(-(bf2f(fr & 0xffffu) + bf)));
            float r = 1.f / (1.f + __expf(-(bf2f(fr >> 16) + br)));
            c = f * c + (1.f - f) * xt;
            float th = 1.f - 2.f / (__expf(2.f * c) + 1.f);
            float h = r * th + (1.f - r) * xp;
            x[idx] = h;
            if (write_bf) xbf[idx] = f2bf(h);
        }
    } else {
        #pragma unroll 8
        for (int t = L_SEQ - 1; t >= 0; t--) {
            size_t idx = base + (size_t)t * stride;
            float xt = u_xt[idx];
            unsigned fr = u_fr32[idx];
            float xp = x[idx];
            float f = 1.f / (1.f + __expf(-(bf2f(fr & 0xffffu) + bf)));
            float r = 1.f / (1.f + __expf(-(bf2f(fr >> 16) + br)));
            c = f * c + (1.f - f) * xt;
            float th = 1.f - 2.f / (__expf(2.f * c) + 1.f);
            float h = r * th + (1.f - r) * xp;
            x[idx] = h;
            if (write_bf) xbf[idx] = f2bf(h);
        }
    }
    c_out[base] = c;
}

// ---------------- launch ----------------
// Inputs: rnn_input(i32 L*B), input_lengths(i32 B, unused), emb(f32), Ws(f32), bs(f32).
// d_out: [ x (L*B*1024) | hidden (4*B*1024) ] f32.
// Workspace (184 MB): u_xt f32 64MB | u_fr bf16 64MB | xbf bf16 32MB | Wt bf16 24MB.
extern "C" void kernel_launch(void* const* d_in, const int* in_sizes, int n_in,
                              void* d_out, int out_size, void* d_ws, size_t ws_size,
                              hipStream_t stream) {
    const int*   tok = (const int*)d_in[0];
    const float* emb = (const float*)d_in[2];
    const float* Ws  = (const float*)d_in[3];
    const float* bs  = (const float*)d_in[4];

    float* out    = (float*)d_out;
    float* x      = out;
    float* hidden = out + (size_t)NTOK * DIN;

    char* ws = (char*)d_ws;
    float*          u_xt = (float*)ws;                                  // 64 MB
    unsigned short* u_fr = (unsigned short*)(ws + (64u << 20));         // 64 MB
    unsigned short* xbf  = (unsigned short*)(ws + (128u << 20));        // 32 MB
    unsigned short* Wt   = (unsigned short*)(ws + (160u << 20));        // 24 MB

    transpose_w<<<dim3(NBIG / 32, DIN / 32, NLAYERS), 256, 0, stream>>>(Ws, Wt);
    embed_kernel<<<NTOK, 256, 0, stream>>>(tok, emb, x, xbf);

    for (int l = 0; l < NLAYERS; l++) {
        const unsigned short* Wl = Wt + (size_t)l * NBIG * DIN;
        const float* b = bs + (size_t)l * 4 * NOUT;
        gemm_bf16<<<dim3(NBIG / 128, NTOK / 128), 256, 0, stream>>>(xbf, Wl, u_xt, u_fr);
        sru_scan<<<BATCH * 2 * (NOUT / 64), 64, 0, stream>>>(
            u_xt, (const unsigned*)u_fr, x, xbf, b,
            hidden + (size_t)l * BATCH * DIN, l < NLAYERS - 1);
    }
}

// Round 3
// 1192.285 us; speedup vs baseline: 5.2634x; 2.4961x over previous
//
#include <hip/hip_runtime.h>
#include <hip/hip_bf16.h>
#include <cmath>

// Problem constants
#define L_SEQ  1024
#define BATCH  16
#define NOUT   512          // n
#define DIN    1024         // 2n = layer input dim = GEMM K
#define NBIG   3072         // 6n = GEMM N
#define NLAYERS 4
#define NTOK   (L_SEQ * BATCH)   // 16384 = GEMM M
#define NCHAIN 16384             // B * 2 * n independent scan chains
#define SEG    32                // segments per chain
#define SEGLEN (L_SEQ / SEG)     // 32 steps per segment

typedef __attribute__((ext_vector_type(8))) short bf16x8;
typedef __attribute__((ext_vector_type(4))) float f32x4;

__device__ __forceinline__ unsigned short f2bf(float f) {
    unsigned x = __float_as_uint(f);
    unsigned r = (x + 0x7fffu + ((x >> 16) & 1u)) >> 16;   // RNE
    return (unsigned short)r;
}
__device__ __forceinline__ float bf2f(unsigned short hv) {
    return __uint_as_float((unsigned)hv << 16);
}
__device__ __forceinline__ float sigmf(float v) {
    return 1.f / (1.f + __expf(-v));
}
__device__ __forceinline__ void async16(const void* g, const void* l) {
    __builtin_amdgcn_global_load_lds(
        (const __attribute__((address_space(1))) unsigned int*)g,
        (__attribute__((address_space(3))) unsigned int*)l, 16, 0, 0);
}

// ---------------- W convert + transpose: W(1024,3072) f32 -> Wt(3072,1024) bf16 ----------------
__global__ __launch_bounds__(256)
void transpose_w(const float* __restrict__ Ws, unsigned short* __restrict__ Wt) {
    __shared__ float tile[32][33];
    int l = blockIdx.z;
    const float* W = Ws + (size_t)l * DIN * NBIG;
    unsigned short* Wo = Wt + (size_t)l * NBIG * DIN;
    int n0 = blockIdx.x * 32, k0 = blockIdx.y * 32;
    int tx = threadIdx.x & 31, ty = threadIdx.x >> 5;
    #pragma unroll
    for (int i = 0; i < 4; i++)
        tile[ty + 8 * i][tx] = W[(size_t)(k0 + ty + 8 * i) * NBIG + n0 + tx];
    __syncthreads();
    #pragma unroll
    for (int i = 0; i < 4; i++)
        Wo[(size_t)(n0 + ty + 8 * i) * DIN + k0 + tx] = f2bf(tile[tx][ty + 8 * i]);
}

// ---------------- embedding gather: write x fp32 + xbf bf16 ----------------
__global__ void embed_kernel(const int* __restrict__ tok,
                             const float* __restrict__ emb,
                             float* __restrict__ x,
                             unsigned short* __restrict__ xbf) {
    int t = blockIdx.x;
    int row = tok[t];
    float4 v = ((const float4*)(emb + (size_t)row * DIN))[threadIdx.x];
    ((float4*)(x + (size_t)t * DIN))[threadIdx.x] = v;
    ushort4 h;
    h.x = f2bf(v.x); h.y = f2bf(v.y); h.z = f2bf(v.z); h.w = f2bf(v.w);
    ((ushort4*)(xbf + (size_t)t * DIN))[threadIdx.x] = h;
}

// ---------------- bf16 MFMA GEMM: u = x @ W ----------------
// 128x128 tile, BK=32, 2x2 waves, 4x4 16x16x32 MFMA per wave. global_load_lds w16
// with source-side XOR swizzle (frag ds_read_b128 <=2-way bank alias = free).
// Epilogue splits planes: xt -> u_xt fp32; f -> u_f bf16; r -> u_r bf16,
// each laid out [tok][dir*512 + feat].
__global__ __launch_bounds__(256)
void gemm_bf16(const unsigned short* __restrict__ Abf,
               const unsigned short* __restrict__ Bt,
               float* __restrict__ u_xt,
               unsigned short* __restrict__ u_f,
               unsigned short* __restrict__ u_r) {
    __shared__ __align__(16) unsigned short As[128 * 32];
    __shared__ __align__(16) unsigned short Bs[128 * 32];

    const int tid  = threadIdx.x;
    const int lane = tid & 63;
    const int w    = tid >> 6;
    const int wm   = w & 1, wn = w >> 1;
    const int quad = lane >> 4, l16 = lane & 15;

    const int M0 = blockIdx.y * 128;
    const int N0 = blockIdx.x * 128;

    f32x4 acc[4][4];
    #pragma unroll
    for (int i = 0; i < 4; i++)
        #pragma unroll
        for (int j = 0; j < 4; j++)
            acc[i][j] = (f32x4){0.f, 0.f, 0.f, 0.f};

    const int sr = lane >> 2;                         // row within 16-row group
    const int sc = (lane & 3) ^ ((lane >> 3) & 3);    // swizzled k-chunk

    for (int k0 = 0; k0 < DIN; k0 += 32) {
        #pragma unroll
        for (int s = 0; s < 2; s++) {
            int rbase = w * 32 + s * 16;
            int r = rbase + sr;
            async16(Abf + (size_t)(M0 + r) * DIN + k0 + sc * 8, &As[rbase * 32]);
            async16(Bt  + (size_t)(N0 + r) * DIN + k0 + sc * 8, &Bs[rbase * 32]);
        }
        __syncthreads();

        bf16x8 af[4], bg[4];
        #pragma unroll
        for (int t = 0; t < 4; t++) {
            int ra = wm * 64 + t * 16 + l16;
            int ca = quad ^ ((ra >> 1) & 3);
            af[t] = *(const bf16x8*)&As[ra * 32 + ca * 8];
            int rb = wn * 64 + t * 16 + l16;
            int cb = quad ^ ((rb >> 1) & 3);
            bg[t] = *(const bf16x8*)&Bs[rb * 32 + cb * 8];
        }
        #pragma unroll
        for (int i = 0; i < 4; i++)
            #pragma unroll
            for (int j = 0; j < 4; j++)
                acc[i][j] = __builtin_amdgcn_mfma_f32_16x16x32_bf16(af[i], bg[j], acc[i][j], 0, 0, 0);
        __syncthreads();
    }

    #pragma unroll
    for (int i = 0; i < 4; i++) {
        int gm = M0 + wm * 64 + i * 16 + quad * 4;
        #pragma unroll
        for (int j = 0; j < 4; j++) {
            int gn = N0 + wn * 64 + j * 16 + l16;
            int dir  = gn >= 3 * NOUT;
            int jj   = gn - dir * 3 * NOUT;
            int plane = jj >> 9;          // 0:xt 1:f 2:r (uniform per 16-tile)
            int feat  = jj & 511;
            size_t off = (size_t)gm * DIN + dir * NOUT + feat;
            if (plane == 0) {
                #pragma unroll
                for (int r = 0; r < 4; r++) u_xt[off + (size_t)r * DIN] = acc[i][j][r];
            } else if (plane == 1) {
                #pragma unroll
                for (int r = 0; r < 4; r++) u_f[off + (size_t)r * DIN] = f2bf(acc[i][j][r]);
            } else {
                #pragma unroll
                for (int r = 0; r < 4; r++) u_r[off + (size_t)r * DIN] = f2bf(acc[i][j][r]);
            }
        }
    }
}

// ---------------- chunked SRU scan ----------------
// chain = b*1024 + d*512 + i  (0..16383); element index at time t: t*16384 + chain.
// Segment s covers scan-order steps j=0..31 at t = t0 + sgn*j,
//   d=0: t0 = s*SEGLEN,        sgn=+1
//   d=1: t0 = L-1 - s*SEGLEN,  sgn=-1

// Phase A: per (chain, seg) compute A=prod f, B=scan-from-0 result.
__global__ __launch_bounds__(256)
void scan_phaseA(const float* __restrict__ u_xt, const unsigned short* __restrict__ u_f,
                 const float* __restrict__ bias,
                 float* __restrict__ Aseg, float* __restrict__ Bseg) {
    int g = blockIdx.x * 256 + threadIdx.x;     // s*16384 + chain
    int chain = g & (NCHAIN - 1);
    int s = g >> 14;
    int rest = chain & 1023;                    // d*512 + i
    float bf = bias[rest];

    int d = rest >> 9;
    int t0 = d ? (L_SEQ - 1 - s * SEGLEN) : (s * SEGLEN);
    int sgn = d ? -1 : 1;
    long long idx = (long long)t0 * NCHAIN + chain;
    long long step = (long long)sgn * NCHAIN;

    float c = 0.f, A = 1.f;
    #pragma unroll 8
    for (int j = 0; j < SEGLEN; j++) {
        float xt = u_xt[idx];
        float f = sigmf(bf2f(u_f[idx]) + bf);
        c = f * c + (1.f - f) * xt;
        A *= f;
        idx += step;
    }
    Aseg[g] = A;
    Bseg[g] = c;
}

// Phase B: compose segment carries per chain; write cstart per segment and
// the final c (== hidden state, layout (B,2n) flat == chain).
__global__ __launch_bounds__(256)
void scan_phaseB(const float* __restrict__ Aseg, const float* __restrict__ Bseg,
                 float* __restrict__ cstart, float* __restrict__ c_out) {
    int chain = blockIdx.x * 256 + threadIdx.x;
    float c = 0.f;
    #pragma unroll
    for (int s = 0; s < SEG; s++) {
        int g = s * NCHAIN + chain;
        cstart[g] = c;
        c = Aseg[g] * c + Bseg[g];
    }
    c_out[chain] = c;
}

// Phase C: re-scan each segment from true cstart, emit h (in-place on x) + bf16 copy.
__global__ __launch_bounds__(256)
void scan_phaseC(const float* __restrict__ u_xt, const unsigned short* __restrict__ u_f,
                 const unsigned short* __restrict__ u_r,
                 float* __restrict__ x, unsigned short* __restrict__ xbf,
                 const float* __restrict__ bias, const float* __restrict__ cstart,
                 int write_bf) {
    int g = blockIdx.x * 256 + threadIdx.x;
    int chain = g & (NCHAIN - 1);
    int s = g >> 14;
    int rest = chain & 1023;
    float bf = bias[rest];
    float br = bias[1024 + rest];

    int d = rest >> 9;
    int t0 = d ? (L_SEQ - 1 - s * SEGLEN) : (s * SEGLEN);
    int sgn = d ? -1 : 1;
    long long idx = (long long)t0 * NCHAIN + chain;
    long long step = (long long)sgn * NCHAIN;

    float c = cstart[g];
    #pragma unroll 4
    for (int j = 0; j < SEGLEN; j++) {
        float xt = u_xt[idx];
        float f = sigmf(bf2f(u_f[idx]) + bf);
        float r = sigmf(bf2f(u_r[idx]) + br);
        float xp = x[idx];
        c = f * c + (1.f - f) * xt;
        float th = 1.f - 2.f / (__expf(2.f * c) + 1.f);
        float h = r * th + (1.f - r) * xp;
        x[idx] = h;
        if (write_bf) xbf[idx] = f2bf(h);
        idx += step;
    }
}

// ---------------- launch ----------------
// d_out: [ x (L*B*1024) | hidden (4*B*1024) ] f32.
// Workspace (190 MB): u_xt 64 | u_f 32 | u_r 32 | xbf 32 | Wt 24 | Aseg 2 | Bseg 2 | cstart 2.
extern "C" void kernel_launch(void* const* d_in, const int* in_sizes, int n_in,
                              void* d_out, int out_size, void* d_ws, size_t ws_size,
                              hipStream_t stream) {
    const int*   tok = (const int*)d_in[0];
    const float* emb = (const float*)d_in[2];
    const float* Ws  = (const float*)d_in[3];
    const float* bs  = (const float*)d_in[4];

    float* out    = (float*)d_out;
    float* x      = out;
    float* hidden = out + (size_t)NTOK * DIN;

    char* ws = (char*)d_ws;
    float*          u_xt   = (float*)ws;                                // 64 MB
    unsigned short* u_f    = (unsigned short*)(ws + (64u  << 20));      // 32 MB
    unsigned short* u_r    = (unsigned short*)(ws + (96u  << 20));      // 32 MB
    unsigned short* xbf    = (unsigned short*)(ws + (128u << 20));      // 32 MB
    unsigned short* Wt     = (unsigned short*)(ws + (160u << 20));      // 24 MB
    float*          Aseg   = (float*)(ws + (184u << 20));               // 2 MB
    float*          Bseg   = (float*)(ws + (186u << 20));               // 2 MB
    float*          cstart = (float*)(ws + (188u << 20));               // 2 MB

    transpose_w<<<dim3(NBIG / 32, DIN / 32, NLAYERS), 256, 0, stream>>>(Ws, Wt);
    embed_kernel<<<NTOK, 256, 0, stream>>>(tok, emb, x, xbf);

    const int scan_blocks = NCHAIN * SEG / 256;   // 2048

    for (int l = 0; l < NLAYERS; l++) {
        const unsigned short* Wl = Wt + (size_t)l * NBIG * DIN;
        const float* b = bs + (size_t)l * 4 * NOUT;
        gemm_bf16<<<dim3(NBIG / 128, NTOK / 128), 256, 0, stream>>>(xbf, Wl, u_xt, u_f, u_r);
        scan_phaseA<<<scan_blocks, 256, 0, stream>>>(u_xt, u_f, b, Aseg, Bseg);
        scan_phaseB<<<NCHAIN / 256, 256, 0, stream>>>(Aseg, Bseg, cstart,
                                                      hidden + (size_t)l * BATCH * DIN);
        scan_phaseC<<<scan_blocks, 256, 0, stream>>>(u_xt, u_f, u_r, x, xbf, b, cstart,
                                                     l < NLAYERS - 1);
    }
}

// Round 4
// 961.014 us; speedup vs baseline: 6.5301x; 1.2407x over previous
//
#include <hip/hip_runtime.h>
#include <hip/hip_bf16.h>
#include <cmath>

// Problem constants
#define L_SEQ  1024
#define BATCH  16
#define NOUT   512          // n
#define DIN    1024         // 2n = layer input dim = GEMM K
#define NBIG   3072         // 6n = GEMM N
#define NLAYERS 4
#define NTOK   (L_SEQ * BATCH)   // 16384 = GEMM M
#define NCHAIN 16384             // B * 2 * n independent scan chains
#define SEG    32                // segments per chain
#define SEGLEN (L_SEQ / SEG)     // 32 steps per segment

typedef __attribute__((ext_vector_type(8))) short bf16x8;
typedef __attribute__((ext_vector_type(4))) float f32x4;

__device__ __forceinline__ unsigned short f2bf(float f) {
    unsigned x = __float_as_uint(f);
    unsigned r = (x + 0x7fffu + ((x >> 16) & 1u)) >> 16;   // RNE
    return (unsigned short)r;
}
__device__ __forceinline__ float bf2f(unsigned short hv) {
    return __uint_as_float((unsigned)hv << 16);
}
__device__ __forceinline__ float sigmf(float v) {
    return 1.f / (1.f + __expf(-v));
}
__device__ __forceinline__ void async16(const void* g, const void* l) {
    __builtin_amdgcn_global_load_lds(
        (const __attribute__((address_space(1))) unsigned int*)g,
        (__attribute__((address_space(3))) unsigned int*)l, 16, 0, 0);
}

// ---------------- W convert + transpose: W(1024,3072) f32 -> Wt(3072,1024) bf16 ----------------
__global__ __launch_bounds__(256)
void transpose_w(const float* __restrict__ Ws, unsigned short* __restrict__ Wt) {
    __shared__ float tile[32][33];
    int l = blockIdx.z;
    const float* W = Ws + (size_t)l * DIN * NBIG;
    unsigned short* Wo = Wt + (size_t)l * NBIG * DIN;
    int n0 = blockIdx.x * 32, k0 = blockIdx.y * 32;
    int tx = threadIdx.x & 31, ty = threadIdx.x >> 5;
    #pragma unroll
    for (int i = 0; i < 4; i++)
        tile[ty + 8 * i][tx] = W[(size_t)(k0 + ty + 8 * i) * NBIG + n0 + tx];
    __syncthreads();
    #pragma unroll
    for (int i = 0; i < 4; i++)
        Wo[(size_t)(n0 + ty + 8 * i) * DIN + k0 + tx] = f2bf(tile[tx][ty + 8 * i]);
}

// ---------------- embedding gather: write x fp32 + xbf bf16 ----------------
__global__ void embed_kernel(const int* __restrict__ tok,
                             const float* __restrict__ emb,
                             float* __restrict__ x,
                             unsigned short* __restrict__ xbf) {
    int t = blockIdx.x;
    int row = tok[t];
    float4 v = ((const float4*)(emb + (size_t)row * DIN))[threadIdx.x];
    ((float4*)(x + (size_t)t * DIN))[threadIdx.x] = v;
    ushort4 h;
    h.x = f2bf(v.x); h.y = f2bf(v.y); h.z = f2bf(v.z); h.w = f2bf(v.w);
    ((ushort4*)(xbf + (size_t)t * DIN))[threadIdx.x] = h;
}

// ---------------- bf16 MFMA GEMM: u = x @ W ----------------
// 128x128 tile, BK=64 (16 K-iters, half the barriers of BK=32), 2x2 waves,
// 4x4 16x16x32 MFMA per wave, 2 K-steps per LDS tile.
// LDS row = 64 bf16 = 8 chunks of 16B; chunk lc stored at slot lc ^ (row & 7)
// so frag ds_read_b128 (16 rows, same lc) is <=2-way bank alias per quad = free.
// Staged via global_load_lds w16 with SOURCE-side permutation: lane L of a wave
// covers row rbase+(L>>3), dest slot L&7  ==> source chunk (L&7) ^ (L>>3).
// Epilogue: all three planes (xt, f, r) -> bf16, layout [tok][dir*512 + feat].
__global__ __launch_bounds__(256)
void gemm_bf16(const unsigned short* __restrict__ Abf,
               const unsigned short* __restrict__ Bt,
               unsigned short* __restrict__ u_xt,
               unsigned short* __restrict__ u_f,
               unsigned short* __restrict__ u_r) {
    __shared__ __align__(16) unsigned short As[128 * 64];
    __shared__ __align__(16) unsigned short Bs[128 * 64];

    const int tid  = threadIdx.x;
    const int lane = tid & 63;
    const int w    = tid >> 6;
    const int wm   = w & 1, wn = w >> 1;
    const int quad = lane >> 4, l16 = lane & 15;

    const int M0 = blockIdx.y * 128;
    const int N0 = blockIdx.x * 128;

    f32x4 acc[4][4];
    #pragma unroll
    for (int i = 0; i < 4; i++)
        #pragma unroll
        for (int j = 0; j < 4; j++)
            acc[i][j] = (f32x4){0.f, 0.f, 0.f, 0.f};

    // staging lane coords (8-row groups, 8 chunks/row)
    const int sr = lane >> 3;                 // row within group 0..7
    const int sc = (lane & 7) ^ sr;           // source k-chunk (swizzle inverse)

    for (int k0 = 0; k0 < DIN; k0 += 64) {
        #pragma unroll
        for (int g = 0; g < 4; g++) {
            int rbase = w * 32 + g * 8;       // wave-uniform 8-row group
            int r = rbase + sr;
            async16(Abf + (size_t)(M0 + r) * DIN + k0 + sc * 8, &As[rbase * 64]);
            async16(Bt  + (size_t)(N0 + r) * DIN + k0 + sc * 8, &Bs[rbase * 64]);
        }
        __syncthreads();

        #pragma unroll
        for (int s = 0; s < 2; s++) {
            bf16x8 af[4], bg[4];
            #pragma unroll
            for (int t = 0; t < 4; t++) {
                int ra = wm * 64 + t * 16 + l16;
                int sa = (s * 4 + quad) ^ (ra & 7);
                af[t] = *(const bf16x8*)&As[ra * 64 + sa * 8];
                int rb = wn * 64 + t * 16 + l16;
                int sb = (s * 4 + quad) ^ (rb & 7);
                bg[t] = *(const bf16x8*)&Bs[rb * 64 + sb * 8];
            }
            #pragma unroll
            for (int i = 0; i < 4; i++)
                #pragma unroll
                for (int j = 0; j < 4; j++)
                    acc[i][j] = __builtin_amdgcn_mfma_f32_16x16x32_bf16(af[i], bg[j], acc[i][j], 0, 0, 0);
        }
        __syncthreads();
    }

    #pragma unroll
    for (int i = 0; i < 4; i++) {
        int gm = M0 + wm * 64 + i * 16 + quad * 4;
        #pragma unroll
        for (int j = 0; j < 4; j++) {
            int gn = N0 + wn * 64 + j * 16 + l16;
            int dir  = gn >= 3 * NOUT;
            int jj   = gn - dir * 3 * NOUT;
            int plane = jj >> 9;          // 0:xt 1:f 2:r (uniform per 16-tile)
            int feat  = jj & 511;
            unsigned short* p = (plane == 0 ? u_xt : plane == 1 ? u_f : u_r)
                                + (size_t)gm * DIN + dir * NOUT + feat;
            #pragma unroll
            for (int r = 0; r < 4; r++) p[(size_t)r * DIN] = f2bf(acc[i][j][r]);
        }
    }
}

// ---------------- chunked SRU scan ----------------
// chain = b*1024 + d*512 + i  (0..16383); element index at time t: t*16384 + chain.
// Segment s: steps j=0..31 at t = t0 + sgn*j; d=0: t0=s*32,sgn=+1; d=1: t0=1023-s*32,sgn=-1.

// Phase A: per (chain, seg) compute A=prod f, B=scan-from-0 result.
__global__ __launch_bounds__(256)
void scan_phaseA(const unsigned short* __restrict__ u_xt, const unsigned short* __restrict__ u_f,
                 const float* __restrict__ bias,
                 float* __restrict__ Aseg, float* __restrict__ Bseg) {
    int g = blockIdx.x * 256 + threadIdx.x;     // s*16384 + chain
    int chain = g & (NCHAIN - 1);
    int s = g >> 14;
    int rest = chain & 1023;                    // d*512 + i
    float bf = bias[rest];

    int d = rest >> 9;
    int t0 = d ? (L_SEQ - 1 - s * SEGLEN) : (s * SEGLEN);
    int sgn = d ? -1 : 1;
    long long idx = (long long)t0 * NCHAIN + chain;
    long long step = (long long)sgn * NCHAIN;

    float c = 0.f, A = 1.f;
    #pragma unroll 8
    for (int j = 0; j < SEGLEN; j++) {
        float xt = bf2f(u_xt[idx]);
        float f = sigmf(bf2f(u_f[idx]) + bf);
        c = f * c + (1.f - f) * xt;
        A *= f;
        idx += step;
    }
    Aseg[g] = A;
    Bseg[g] = c;
}

// Phase B: compose segment carries per chain; write cstart per segment and
// the final c (== hidden state, layout (B,2n) flat == chain).
__global__ __launch_bounds__(256)
void scan_phaseB(const float* __restrict__ Aseg, const float* __restrict__ Bseg,
                 float* __restrict__ cstart, float* __restrict__ c_out) {
    int chain = blockIdx.x * 256 + threadIdx.x;
    float c = 0.f;
    #pragma unroll
    for (int s = 0; s < SEG; s++) {
        int g = s * NCHAIN + chain;
        cstart[g] = c;
        c = Aseg[g] * c + Bseg[g];
    }
    c_out[chain] = c;
}

// Phase C: re-scan each segment from true cstart, emit h (in-place on x) + bf16 copy.
__global__ __launch_bounds__(256)
void scan_phaseC(const unsigned short* __restrict__ u_xt, const unsigned short* __restrict__ u_f,
                 const unsigned short* __restrict__ u_r,
                 float* __restrict__ x, unsigned short* __restrict__ xbf,
                 const float* __restrict__ bias, const float* __restrict__ cstart,
                 int write_bf) {
    int g = blockIdx.x * 256 + threadIdx.x;
    int chain = g & (NCHAIN - 1);
    int s = g >> 14;
    int rest = chain & 1023;
    float bf = bias[rest];
    float br = bias[1024 + rest];

    int d = rest >> 9;
    int t0 = d ? (L_SEQ - 1 - s * SEGLEN) : (s * SEGLEN);
    int sgn = d ? -1 : 1;
    long long idx = (long long)t0 * NCHAIN + chain;
    long long step = (long long)sgn * NCHAIN;

    float c = cstart[g];
    #pragma unroll 4
    for (int j = 0; j < SEGLEN; j++) {
        float xt = bf2f(u_xt[idx]);
        float f = sigmf(bf2f(u_f[idx]) + bf);
        float r = sigmf(bf2f(u_r[idx]) + br);
        float xp = x[idx];
        c = f * c + (1.f - f) * xt;
        float th = 1.f - 2.f / (__expf(2.f * c) + 1.f);
        float h = r * th + (1.f - r) * xp;
        x[idx] = h;
        if (write_bf) xbf[idx] = f2bf(h);
        idx += step;
    }
}

// ---------------- launch ----------------
// d_out: [ x (L*B*1024) | hidden (4*B*1024) ] f32.
// Workspace (158 MB): u_xt 32 | u_f 32 | u_r 32 | xbf 32 | Wt 24 | Aseg 2 | Bseg 2 | cstart 2.
extern "C" void kernel_launch(void* const* d_in, const int* in_sizes, int n_in,
                              void* d_out, int out_size, void* d_ws, size_t ws_size,
                              hipStream_t stream) {
    const int*   tok = (const int*)d_in[0];
    const float* emb = (const float*)d_in[2];
    const float* Ws  = (const float*)d_in[3];
    const float* bs  = (const float*)d_in[4];

    float* out    = (float*)d_out;
    float* x      = out;
    float* hidden = out + (size_t)NTOK * DIN;

    char* ws = (char*)d_ws;
    unsigned short* u_xt   = (unsigned short*)ws;                       // 32 MB
    unsigned short* u_f    = (unsigned short*)(ws + (32u  << 20));      // 32 MB
    unsigned short* u_r    = (unsigned short*)(ws + (64u  << 20));      // 32 MB
    unsigned short* xbf    = (unsigned short*)(ws + (96u  << 20));      // 32 MB
    unsigned short* Wt     = (unsigned short*)(ws + (128u << 20));      // 24 MB
    float*          Aseg   = (float*)(ws + (152u << 20));               // 2 MB
    float*          Bseg   = (float*)(ws + (154u << 20));               // 2 MB
    float*          cstart = (float*)(ws + (156u << 20));               // 2 MB

    transpose_w<<<dim3(NBIG / 32, DIN / 32, NLAYERS), 256, 0, stream>>>(Ws, Wt);
    embed_kernel<<<NTOK, 256, 0, stream>>>(tok, emb, x, xbf);

    const int scan_blocks = NCHAIN * SEG / 256;   // 2048

    for (int l = 0; l < NLAYERS; l++) {
        const unsigned short* Wl = Wt + (size_t)l * NBIG * DIN;
        const float* b = bs + (size_t)l * 4 * NOUT;
        gemm_bf16<<<dim3(NBIG / 128, NTOK / 128), 256, 0, stream>>>(xbf, Wl, u_xt, u_f, u_r);
        scan_phaseA<<<scan_blocks, 256, 0, stream>>>(u_xt, u_f, b, Aseg, Bseg);
        scan_phaseB<<<NCHAIN / 256, 256, 0, stream>>>(Aseg, Bseg, cstart,
                                                      hidden + (size_t)l * BATCH * DIN);
        scan_phaseC<<<scan_blocks, 256, 0, stream>>>(u_xt, u_f, u_r, x, xbf, b, cstart,
                                                     l < NLAYERS - 1);
    }
}